// Round 6
// baseline (473.748 us; speedup 1.0000x reference)
//
#include <hip/hip_runtime.h>

// 2-layer LSTM (B=512, T=300, D=80, H=128) + FC head on MI355X.
// Round 3: producer/consumer layer pipeline across 64 WGs.
//   WG 0..31  = layer 0 for batch tile wg   (producer)
//   WG 32..63 = layer 1 + FC for tile wg-32 (consumer, lags 1 step)
// h1 handed off through LLC via sc0/sc1 bypass stores/loads + per-step flags
// (relaxed agent atomics). Producer never waits on consumer -> deadlock-free.

typedef _Float16 f16;
typedef _Float16 f16x8 __attribute__((ext_vector_type(8)));
typedef float f32x4 __attribute__((ext_vector_type(4)));

#define T_SEQ 300
#define D_IN  80
#define HDIM  128
#define B_ALL 512
#define B_TILE 16
#define N_PROD 32
#define N_WG_TOT 64

#define XT_BYTES  ((size_t)B_ALL * T_SEQ * D_IN * 2)   // 24,576,000
#define H1_BYTES  ((size_t)T_SEQ * B_ALL * HDIM * 2)   // 39,321,600
#define FLAGS_OFF (XT_BYTES + H1_BYTES)
#define FLAGS_BYTES ((size_t)N_PROD * T_SEQ * 4)       // 38,400
#define HSTEP_BYTES ((uint64_t)B_ALL * HDIM * 2)       // 131072

// LLC-coherent (bypass vL1/L2) 16B load with immediate offset.
#define LLC_LOAD(dst, addr, OFFSTR)                                        \
    asm volatile("global_load_dwordx4 %0, %1, off offset:" OFFSTR " sc0 sc1" \
                 : "=v"(dst) : "v"(addr) : "memory")
// LLC-coherent 2B store with immediate offset.
#define LLC_STORE_SHORT(addr, val, OFFSTR)                                 \
    asm volatile("global_store_short %0, %1, off offset:" OFFSTR " sc0 sc1" \
                 :: "v"(addr), "v"(val) : "memory")

__device__ __forceinline__ float sigm(float x) {
    return __builtin_amdgcn_rcpf(1.0f + __builtin_amdgcn_exp2f(-1.44269504f * x));
}
__device__ __forceinline__ float tanh_fast(float x) {
    return 1.0f - 2.0f * __builtin_amdgcn_rcpf(1.0f + __builtin_amdgcn_exp2f(2.88539008f * x));
}

__device__ __forceinline__ void wg_barrier_lds() {
    asm volatile("s_waitcnt lgkmcnt(0)" ::: "memory");
    __builtin_amdgcn_sched_barrier(0);
    __builtin_amdgcn_s_barrier();
    __builtin_amdgcn_sched_barrier(0);
}

__device__ __forceinline__ int flag_ld(const int* p) {
    return __hip_atomic_load(p, __ATOMIC_RELAXED, __HIP_MEMORY_SCOPE_AGENT);
}

// ---------------- prep: x (B,D,T) f32 -> xT (B,T,80) f16
__global__ __launch_bounds__(256) void k_prep(const float* __restrict__ x,
                                              f16* __restrict__ xT) {
    __shared__ f16 tile[D_IN][T_SEQ + 8];
    const int b = blockIdx.x;
    const int tid = threadIdx.x;
    const float* xb = x + (size_t)b * D_IN * T_SEQ;
    for (int i = tid; i < D_IN * T_SEQ; i += 256) {
        int d = i / T_SEQ;
        int t = i - d * T_SEQ;
        tile[d][t] = (f16)xb[i];
    }
    __syncthreads();
    f16* outb = xT + (size_t)b * T_SEQ * D_IN;
    for (int i = tid; i < T_SEQ * (D_IN / 8); i += 256) {
        int t  = i / (D_IN / 8);
        int dc = i - t * (D_IN / 8);
        f16x8 v;
#pragma unroll
        for (int e = 0; e < 8; ++e) v[e] = tile[dc * 8 + e][t];
        *(f16x8*)(outb + t * D_IN + dc * 8) = v;
    }
}

// Build a B-fragment (gate row `row` of W, k-range [k0,k0+8), zero beyond kmax)
__device__ __forceinline__ f16x8 load_wfrag(const float* __restrict__ W,
                                            int row, int ld, int k0, int kmax) {
    f16x8 v;
#pragma unroll
    for (int e = 0; e < 8; ++e) {
        int k = k0 + e;
        v[e] = (k < kmax) ? (f16)W[row * ld + k] : (f16)0.0f;
    }
    return v;
}

__global__ __launch_bounds__(512, 2) void k_lstm(
    const f16* __restrict__ xT, f16* __restrict__ h1ws, int* __restrict__ flags,
    const float* __restrict__ Wih0, const float* __restrict__ Whh0,
    const float* __restrict__ bih0, const float* __restrict__ bhh0,
    const float* __restrict__ Wih1, const float* __restrict__ Whh1,
    const float* __restrict__ bih1, const float* __restrict__ bhh1,
    const float* __restrict__ fc1w, const float* __restrict__ fc1b,
    const float* __restrict__ fc2w, const float* __restrict__ fc2b,
    const float* __restrict__ fc3w, const float* __restrict__ fc3b,
    float* __restrict__ out)
{
    const int tid = threadIdx.x;
    const int wv  = tid >> 6;
    const int l   = tid & 63;
    const int l16 = l & 15;
    const int lg  = l >> 4;
    const int wg  = blockIdx.x;
    const int u   = wv * 16 + l16;

    __shared__ __align__(16) f16 hbuf[2][16 * HDIM];
    __shared__ float h2buf[16][HDIM];
    __shared__ float a1buf[16][64];
    __shared__ float a2buf[16][33];

    for (int i = tid; i < 16 * HDIM; i += 512) hbuf[0][i] = (f16)0.0f;

    float cst[4] = {0.f, 0.f, 0.f, 0.f};

    if (wg < N_PROD) {
        // ===================== PRODUCER: layer 0 =====================
        const int wgb = wg;
        f16x8 wih[4][3], whh[4][4];
        float biasv[4];
#pragma unroll
        for (int nt = 0; nt < 4; ++nt) {
            int gate = nt * 128 + u;
            biasv[nt] = bih0[gate] + bhh0[gate];
#pragma unroll
            for (int kc = 0; kc < 4; ++kc)
                whh[nt][kc] = load_wfrag(Whh0, gate, HDIM, kc * 32 + lg * 8, HDIM);
#pragma unroll
            for (int kc = 0; kc < 3; ++kc)
                wih[nt][kc] = load_wfrag(Wih0, gate, D_IN, kc * 32 + lg * 8, D_IN);
        }
        __syncthreads();

        // x rows are 80 f16 = 160B; kc=2 reads k=64..95, lanes lg>=2 read
        // garbage beyond the row -- harmless, their weight k-rows are zero.
        const f16* xrow = xT + (size_t)(wgb * B_TILE + l16) * T_SEQ * D_IN + lg * 8;
        uint64_t haddr = (uint64_t)(uintptr_t)h1ws +
                         (((uint64_t)wgb * B_TILE + lg * 4) * HDIM + u) * 2;
        int* myflags = flags + wgb * T_SEQ;

        f16x8 xc0 = *(const f16x8*)(xrow);
        f16x8 xc1 = *(const f16x8*)(xrow + 32);
        f16x8 xc2 = *(const f16x8*)(xrow + 64);

        for (int t = 0; t < T_SEQ; ++t) {
            int tn = (t < T_SEQ - 1) ? t + 1 : t;
            const f16* xp = xrow + tn * D_IN;
            f16x8 xn0 = *(const f16x8*)(xp);
            f16x8 xn1 = *(const f16x8*)(xp + 32);
            f16x8 xn2 = *(const f16x8*)(xp + 64);

            const f16* cur = hbuf[t & 1];
            f16* nxt = hbuf[(t + 1) & 1];
            f16x8 ha[4];
#pragma unroll
            for (int kc = 0; kc < 4; ++kc) {
                int chunk = kc * 4 + lg;
                ha[kc] = *(const f16x8*)(cur + l16 * HDIM + ((chunk ^ (l16 & 7)) << 3));
            }
            f32x4 acc[4];
#pragma unroll
            for (int nt = 0; nt < 4; ++nt) {
                f32x4 a = {biasv[nt], biasv[nt], biasv[nt], biasv[nt]};
                a = __builtin_amdgcn_mfma_f32_16x16x32_f16(xc0, wih[nt][0], a, 0, 0, 0);
                a = __builtin_amdgcn_mfma_f32_16x16x32_f16(xc1, wih[nt][1], a, 0, 0, 0);
                a = __builtin_amdgcn_mfma_f32_16x16x32_f16(xc2, wih[nt][2], a, 0, 0, 0);
                a = __builtin_amdgcn_mfma_f32_16x16x32_f16(ha[0], whh[nt][0], a, 0, 0, 0);
                a = __builtin_amdgcn_mfma_f32_16x16x32_f16(ha[1], whh[nt][1], a, 0, 0, 0);
                a = __builtin_amdgcn_mfma_f32_16x16x32_f16(ha[2], whh[nt][2], a, 0, 0, 0);
                a = __builtin_amdgcn_mfma_f32_16x16x32_f16(ha[3], whh[nt][3], a, 0, 0, 0);
                acc[nt] = a;
            }
            unsigned hv[4];
#pragma unroll
            for (int r = 0; r < 4; ++r) {
                float iv = sigm(acc[0][r]);
                float fv = sigm(acc[1][r]);
                float gv = tanh_fast(acc[2][r]);
                float ov = sigm(acc[3][r]);
                float cn = fv * cst[r] + iv * gv;
                cst[r] = cn;
                f16 hh = (f16)(ov * tanh_fast(cn));
                int br = lg * 4 + r;
                nxt[br * HDIM + ((((unsigned)u >> 3) ^ (br & 7)) << 3) + (u & 7)] = hh;
                hv[r] = (unsigned)__builtin_bit_cast(unsigned short, hh);
            }
            // h1[t][b][u] handoff rows (br = lg*4 + 0..3, row stride 256B)
            LLC_STORE_SHORT(haddr, hv[0], "0");
            LLC_STORE_SHORT(haddr, hv[1], "256");
            LLC_STORE_SHORT(haddr, hv[2], "512");
            LLC_STORE_SHORT(haddr, hv[3], "768");
            haddr += HSTEP_BYTES;
            xc0 = xn0; xc1 = xn1; xc2 = xn2;

            // drain handoff stores (+prefetch loads), then publish flag[t]
            asm volatile("s_waitcnt vmcnt(0) lgkmcnt(0)" ::: "memory");
            __builtin_amdgcn_sched_barrier(0);
            __builtin_amdgcn_s_barrier();
            __builtin_amdgcn_sched_barrier(0);
            if (tid == 0)
                __hip_atomic_store(&myflags[t], 1, __ATOMIC_RELAXED,
                                   __HIP_MEMORY_SCOPE_AGENT);
        }
        return;  // producers done
    }

    // ===================== CONSUMER: layer 1 + FC =====================
    {
        const int wgb = wg - N_PROD;
        f16x8 wih[4][4], whh[4][4];
        float biasv[4];
#pragma unroll
        for (int nt = 0; nt < 4; ++nt) {
            int gate = nt * 128 + u;
            biasv[nt] = bih1[gate] + bhh1[gate];
#pragma unroll
            for (int kc = 0; kc < 4; ++kc) {
                wih[nt][kc] = load_wfrag(Wih1, gate, HDIM, kc * 32 + lg * 8, HDIM);
                whh[nt][kc] = load_wfrag(Whh1, gate, HDIM, kc * 32 + lg * 8, HDIM);
            }
        }
        __syncthreads();  // hbuf zeros visible

        int* myflags = flags + wgb * T_SEQ;
        // wait for h1[0]
        if (tid == 0) { while (flag_ld(&myflags[0]) == 0) {} }
        __syncthreads();

        uint64_t xaddr = (uint64_t)(uintptr_t)h1ws +
                         ((uint64_t)(wgb * B_TILE + l16) * HDIM) * 2 + lg * 16;
        f16x8 xn0, xn1, xn2, xn3;
        LLC_LOAD(xn0, xaddr, "0");
        LLC_LOAD(xn1, xaddr, "64");
        LLC_LOAD(xn2, xaddr, "128");
        LLC_LOAD(xn3, xaddr, "192");

        float hlast[4] = {0.f, 0.f, 0.f, 0.f};

        for (int t = 0; t < T_SEQ; ++t) {
            asm volatile("s_waitcnt vmcnt(0)" ::: "memory");  // xn ready
            __builtin_amdgcn_sched_barrier(0);

            int probe = 1;
            if (t < T_SEQ - 1)
                probe = flag_ld(&myflags[t + 1]);  // latency hides under MFMA

            const f16* cur = hbuf[t & 1];
            f16* nxt = hbuf[(t + 1) & 1];
            f16x8 ha[4];
#pragma unroll
            for (int kc = 0; kc < 4; ++kc) {
                int chunk = kc * 4 + lg;
                ha[kc] = *(const f16x8*)(cur + l16 * HDIM + ((chunk ^ (l16 & 7)) << 3));
            }
            f32x4 acc[4];
#pragma unroll
            for (int nt = 0; nt < 4; ++nt) {
                f32x4 a = {biasv[nt], biasv[nt], biasv[nt], biasv[nt]};
                a = __builtin_amdgcn_mfma_f32_16x16x32_f16(xn0, wih[nt][0], a, 0, 0, 0);
                a = __builtin_amdgcn_mfma_f32_16x16x32_f16(xn1, wih[nt][1], a, 0, 0, 0);
                a = __builtin_amdgcn_mfma_f32_16x16x32_f16(xn2, wih[nt][2], a, 0, 0, 0);
                a = __builtin_amdgcn_mfma_f32_16x16x32_f16(xn3, wih[nt][3], a, 0, 0, 0);
                a = __builtin_amdgcn_mfma_f32_16x16x32_f16(ha[0], whh[nt][0], a, 0, 0, 0);
                a = __builtin_amdgcn_mfma_f32_16x16x32_f16(ha[1], whh[nt][1], a, 0, 0, 0);
                a = __builtin_amdgcn_mfma_f32_16x16x32_f16(ha[2], whh[nt][2], a, 0, 0, 0);
                a = __builtin_amdgcn_mfma_f32_16x16x32_f16(ha[3], whh[nt][3], a, 0, 0, 0);
                acc[nt] = a;
            }

            if (t < T_SEQ - 1) {
                if (!probe) { while (flag_ld(&myflags[t + 1]) == 0) {} }
                xaddr += HSTEP_BYTES;
                LLC_LOAD(xn0, xaddr, "0");
                LLC_LOAD(xn1, xaddr, "64");
                LLC_LOAD(xn2, xaddr, "128");
                LLC_LOAD(xn3, xaddr, "192");
            }

#pragma unroll
            for (int r = 0; r < 4; ++r) {
                float iv = sigm(acc[0][r]);
                float fv = sigm(acc[1][r]);
                float gv = tanh_fast(acc[2][r]);
                float ov = sigm(acc[3][r]);
                float cn = fv * cst[r] + iv * gv;
                cst[r] = cn;
                float hv = ov * tanh_fast(cn);
                hlast[r] = hv;
                int br = lg * 4 + r;
                nxt[br * HDIM + ((((unsigned)u >> 3) ^ (br & 7)) << 3) + (u & 7)] = (f16)hv;
            }
            wg_barrier_lds();
        }

        // ================= FC head on h2[:, T-1, :] =================
#pragma unroll
        for (int r = 0; r < 4; ++r) h2buf[lg * 4 + r][u] = hlast[r];
        __syncthreads();

        for (int i = tid; i < 16 * 64; i += 512) {
            int b = i >> 6, o = i & 63;
            float s = fc1b[o];
            for (int k = 0; k < HDIM; ++k) s += h2buf[b][k] * fc1w[o * HDIM + k];
            a1buf[b][o] = fmaxf(s, 0.f);
        }
        __syncthreads();
        if (tid < 16 * 32) {
            int b = tid >> 5, o = tid & 31;
            float s = fc2b[o];
            for (int k = 0; k < 64; ++k) s += a1buf[b][k] * fc2w[o * 64 + k];
            a2buf[b][o] = fmaxf(s, 0.f);
        }
        __syncthreads();
        if (tid < 32) {
            int b = tid >> 1, o = tid & 1;
            float s = fc3b[o];
            for (int k = 0; k < 32; ++k) s += a2buf[b][k] * fc3w[o * 32 + k];
            out[(wgb * B_TILE + b) * 2 + o] = s;
        }
    }
}

extern "C" void kernel_launch(void* const* d_in, const int* in_sizes, int n_in,
                              void* d_out, int out_size, void* d_ws, size_t ws_size,
                              hipStream_t stream)
{
    const float* x    = (const float*)d_in[0];
    const float* Wih0 = (const float*)d_in[1];
    const float* Whh0 = (const float*)d_in[2];
    const float* bih0 = (const float*)d_in[3];
    const float* bhh0 = (const float*)d_in[4];
    const float* Wih1 = (const float*)d_in[5];
    const float* Whh1 = (const float*)d_in[6];
    const float* bih1 = (const float*)d_in[7];
    const float* bhh1 = (const float*)d_in[8];
    const float* fc1w = (const float*)d_in[9];
    const float* fc1b = (const float*)d_in[10];
    const float* fc2w = (const float*)d_in[11];
    const float* fc2b = (const float*)d_in[12];
    const float* fc3w = (const float*)d_in[13];
    const float* fc3b = (const float*)d_in[14];

    f16* xT    = (f16*)d_ws;
    f16* h1    = (f16*)((char*)d_ws + XT_BYTES);
    int* flags = (int*)((char*)d_ws + FLAGS_OFF);

    // flags must be zero at the start of every launch (replays included)
    hipMemsetAsync(flags, 0, FLAGS_BYTES, stream);
    k_prep<<<B_ALL, 256, 0, stream>>>(x, xT);
    k_lstm<<<N_WG_TOT, 512, 0, stream>>>(xT, h1, flags, Wih0, Whh0, bih0, bhh0,
                                         Wih1, Whh1, bih1, bhh1,
                                         fc1w, fc1b, fc2w, fc2b, fc3w, fc3b,
                                         (float*)d_out);
}

// Round 7
// 438.556 us; speedup vs baseline: 1.0802x; 1.0802x over previous
//
#include <hip/hip_runtime.h>

// 2-layer LSTM (B=512, T=300, D=80, H=128) + FC head on MI355X.
// Round 7: producer/consumer layer pipeline (64 WGs) with fully-hidden handoff.
//  - producer: handoff store of h1[t-1] at step top (coalesced dwordx2 from LDS),
//    x prefetch right after; ONE vmcnt(0) per step placed after ~700cy of compute
//    so it only drains old ops; then publish flag[t-1]. Producer never waits on
//    consumer (deadlock-free).
//  - consumer: 2-deep prefetch (A/B reg sets, unrolled x2) + early flag probe;
//    ONE vmcnt(0) per step draining only >=1-step-old loads.
// All recurrent-loop VMEM is inline asm; sched_barrier(0) fences after waitcnts.

typedef _Float16 f16;
typedef _Float16 f16x8 __attribute__((ext_vector_type(8)));
typedef float f32x4 __attribute__((ext_vector_type(4)));
typedef unsigned u32x2 __attribute__((ext_vector_type(2)));

#define T_SEQ 300
#define D_IN  80
#define HDIM  128
#define B_ALL 512
#define B_TILE 16
#define N_PROD 32
#define N_WG_TOT 64

#define XT_BYTES  ((size_t)B_ALL * T_SEQ * D_IN * 2)   // 24,576,000
#define H1_BYTES  ((size_t)T_SEQ * B_ALL * HDIM * 2)   // 39,321,600
#define FLAGS_OFF (XT_BYTES + H1_BYTES)
#define FLAGS_BYTES ((size_t)N_PROD * T_SEQ * 4)       // 38,400
#define HSTEP_BYTES ((uint64_t)B_ALL * HDIM * 2)       // 131072

__device__ __forceinline__ float sigm(float x) {
    return __builtin_amdgcn_rcpf(1.0f + __builtin_amdgcn_exp2f(-1.44269504f * x));
}
__device__ __forceinline__ float tanh_fast(float x) {
    return 1.0f - 2.0f * __builtin_amdgcn_rcpf(1.0f + __builtin_amdgcn_exp2f(2.88539008f * x));
}

__device__ __forceinline__ void wg_barrier_lds() {
    asm volatile("s_waitcnt lgkmcnt(0)" ::: "memory");
    __builtin_amdgcn_sched_barrier(0);
    __builtin_amdgcn_s_barrier();
    __builtin_amdgcn_sched_barrier(0);
}
__device__ __forceinline__ void vm_drain() {
    asm volatile("s_waitcnt vmcnt(0)" ::: "memory");
    __builtin_amdgcn_sched_barrier(0);
}

// ---------------- prep: x (B,D,T) f32 -> xT (B,T,80) f16
__global__ __launch_bounds__(256) void k_prep(const float* __restrict__ x,
                                              f16* __restrict__ xT) {
    __shared__ f16 tile[D_IN][T_SEQ + 8];
    const int b = blockIdx.x;
    const int tid = threadIdx.x;
    const float* xb = x + (size_t)b * D_IN * T_SEQ;
    for (int i = tid; i < D_IN * T_SEQ; i += 256) {
        int d = i / T_SEQ;
        int t = i - d * T_SEQ;
        tile[d][t] = (f16)xb[i];
    }
    __syncthreads();
    f16* outb = xT + (size_t)b * T_SEQ * D_IN;
    for (int i = tid; i < T_SEQ * (D_IN / 8); i += 256) {
        int t  = i / (D_IN / 8);
        int dc = i - t * (D_IN / 8);
        f16x8 v;
#pragma unroll
        for (int e = 0; e < 8; ++e) v[e] = tile[dc * 8 + e][t];
        *(f16x8*)(outb + t * D_IN + dc * 8) = v;
    }
}

__device__ __forceinline__ f16x8 load_wfrag(const float* __restrict__ W,
                                            int row, int ld, int k0, int kmax) {
    f16x8 v;
#pragma unroll
    for (int e = 0; e < 8; ++e) {
        int k = k0 + e;
        v[e] = (k < kmax) ? (f16)W[row * ld + k] : (f16)0.0f;
    }
    return v;
}

__global__ __launch_bounds__(512, 2) void k_lstm(
    const f16* __restrict__ xT, f16* __restrict__ h1ws, int* __restrict__ flags,
    const float* __restrict__ Wih0, const float* __restrict__ Whh0,
    const float* __restrict__ bih0, const float* __restrict__ bhh0,
    const float* __restrict__ Wih1, const float* __restrict__ Whh1,
    const float* __restrict__ bih1, const float* __restrict__ bhh1,
    const float* __restrict__ fc1w, const float* __restrict__ fc1b,
    const float* __restrict__ fc2w, const float* __restrict__ fc2b,
    const float* __restrict__ fc3w, const float* __restrict__ fc3b,
    float* __restrict__ out)
{
    const int tid = threadIdx.x;
    const int wv  = tid >> 6;
    const int l   = tid & 63;
    const int l16 = l & 15;
    const int lg  = l >> 4;
    const int wg  = blockIdx.x;
    const int u   = wv * 16 + l16;

    __shared__ __align__(16) f16 hbuf[2][16 * HDIM];
    __shared__ float h2buf[16][HDIM];
    __shared__ float a1buf[16][64];
    __shared__ float a2buf[16][33];

    for (int i = tid; i < 16 * HDIM; i += 512) hbuf[0][i] = (f16)0.0f;

    float cst[4] = {0.f, 0.f, 0.f, 0.f};

    if (wg < N_PROD) {
        // ===================== PRODUCER: layer 0 =====================
        const int wgb = wg;
        f16x8 wih[4][3], whh[4][4];
        float biasv[4];
#pragma unroll
        for (int nt = 0; nt < 4; ++nt) {
            int gate = nt * 128 + u;
            biasv[nt] = bih0[gate] + bhh0[gate];
#pragma unroll
            for (int kc = 0; kc < 4; ++kc)
                whh[nt][kc] = load_wfrag(Whh0, gate, HDIM, kc * 32 + lg * 8, HDIM);
#pragma unroll
            for (int kc = 0; kc < 3; ++kc)
                wih[nt][kc] = load_wfrag(Wih0, gate, D_IN, kc * 32 + lg * 8, D_IN);
        }
        __syncthreads();  // hbuf[0] zeros visible

        const uint64_t xrowu = (uint64_t)(uintptr_t)xT +
                               (uint64_t)(wgb * B_TILE + l16) * T_SEQ * (D_IN * 2) +
                               (uint64_t)lg * 16;
        const uint64_t h1u   = (uint64_t)(uintptr_t)h1ws;
        const uint64_t flagu = (uint64_t)(uintptr_t)(flags + wgb * T_SEQ);
        // handoff-store geometry: thread -> (row br, 8 bytes at col-byte ob)
        const int sbr = tid >> 5;
        const int sob = (tid & 31) * 8;
        const int sswz = (((sob >> 4) ^ (sbr & 7)) << 4) + (sob & 8);
        const uint64_t sdst0 = h1u + (uint64_t)(wgb * B_TILE + sbr) * 256 + (sob & ~7);

        // preload x(0)
        f16x8 xc0, xc1, xc2;
        asm volatile("global_load_dwordx4 %0, %1, off"            : "=v"(xc0) : "v"(xrowu) : "memory");
        asm volatile("global_load_dwordx4 %0, %1, off offset:64"  : "=v"(xc1) : "v"(xrowu) : "memory");
        asm volatile("global_load_dwordx4 %0, %1, off offset:128" : "=v"(xc2) : "v"(xrowu) : "memory");
        vm_drain();

        for (int t = 0; t < T_SEQ; ++t) {
            const f16* cur = hbuf[t & 1];
            f16* nxt = hbuf[(t + 1) & 1];

            // (0a) handoff-store h1[t-1] from LDS (coalesced 8B/lane)
            if (t > 0) {
                u32x2 hval = *(const u32x2*)((const char*)cur + sbr * 256 + sswz);
                uint64_t dst = sdst0 + (uint64_t)(t - 1) * HSTEP_BYTES;
                asm volatile("global_store_dwordx2 %0, %1, off sc0 sc1"
                             :: "v"(dst), "v"(hval) : "memory");
            }
            // (0b) x prefetch for t+1 (plain loads, L2-cached)
            int tn = (t < T_SEQ - 1) ? t + 1 : t;
            uint64_t xa = xrowu + (uint64_t)tn * (D_IN * 2);
            f16x8 xn0, xn1, xn2;
            asm volatile("global_load_dwordx4 %0, %1, off"            : "=v"(xn0) : "v"(xa) : "memory");
            asm volatile("global_load_dwordx4 %0, %1, off offset:64"  : "=v"(xn1) : "v"(xa) : "memory");
            asm volatile("global_load_dwordx4 %0, %1, off offset:128" : "=v"(xn2) : "v"(xa) : "memory");

            // (1) recurrent MFMA + activations
            f16x8 ha[4];
#pragma unroll
            for (int kc = 0; kc < 4; ++kc) {
                int chunk = kc * 4 + lg;
                ha[kc] = *(const f16x8*)(cur + l16 * HDIM + ((chunk ^ (l16 & 7)) << 3));
            }
            f32x4 acc[4];
#pragma unroll
            for (int nt = 0; nt < 4; ++nt) {
                f32x4 a = {biasv[nt], biasv[nt], biasv[nt], biasv[nt]};
                a = __builtin_amdgcn_mfma_f32_16x16x32_f16(xc0, wih[nt][0], a, 0, 0, 0);
                a = __builtin_amdgcn_mfma_f32_16x16x32_f16(xc1, wih[nt][1], a, 0, 0, 0);
                a = __builtin_amdgcn_mfma_f32_16x16x32_f16(xc2, wih[nt][2], a, 0, 0, 0);
                a = __builtin_amdgcn_mfma_f32_16x16x32_f16(ha[0], whh[nt][0], a, 0, 0, 0);
                a = __builtin_amdgcn_mfma_f32_16x16x32_f16(ha[1], whh[nt][1], a, 0, 0, 0);
                a = __builtin_amdgcn_mfma_f32_16x16x32_f16(ha[2], whh[nt][2], a, 0, 0, 0);
                a = __builtin_amdgcn_mfma_f32_16x16x32_f16(ha[3], whh[nt][3], a, 0, 0, 0);
                acc[nt] = a;
            }
#pragma unroll
            for (int r = 0; r < 4; ++r) {
                float iv = sigm(acc[0][r]);
                float fv = sigm(acc[1][r]);
                float gv = tanh_fast(acc[2][r]);
                float ov = sigm(acc[3][r]);
                float cn = fv * cst[r] + iv * gv;
                cst[r] = cn;
                f16 hh = (f16)(ov * tanh_fast(cn));
                int br = lg * 4 + r;
                nxt[br * HDIM + ((((unsigned)u >> 3) ^ (br & 7)) << 3) + (u & 7)] = hh;
            }

            // (2) single drain: everything outstanding is ~700cy old -> hidden.
            // Guarantees h1[t-1] stores complete; publish flag[t-1].
            vm_drain();
            if (t > 0) {
                unsigned one = 1;
                uint64_t fa = flagu + (uint64_t)(t - 1) * 4;
                asm volatile("global_store_dword %0, %1, off sc0 sc1"
                             :: "v"(fa), "v"(one) : "memory");
            }
            xc0 = xn0; xc1 = xn1; xc2 = xn2;
            wg_barrier_lds();
        }
        // tail: store h1[T-1] (in hbuf[T_SEQ&1]) and publish flag[T-1]
        {
            const f16* cur = hbuf[T_SEQ & 1];
            u32x2 hval = *(const u32x2*)((const char*)cur + sbr * 256 + sswz);
            uint64_t dst = sdst0 + (uint64_t)(T_SEQ - 1) * HSTEP_BYTES;
            asm volatile("global_store_dwordx2 %0, %1, off sc0 sc1"
                         :: "v"(dst), "v"(hval) : "memory");
            vm_drain();
            unsigned one = 1;
            uint64_t fa = flagu + (uint64_t)(T_SEQ - 1) * 4;
            asm volatile("global_store_dword %0, %1, off sc0 sc1"
                         :: "v"(fa), "v"(one) : "memory");
        }
        return;
    }

    // ===================== CONSUMER: layer 1 + FC =====================
    {
        const int wgb = wg - N_PROD;
        f16x8 wih[4][4], whh[4][4];
        float biasv[4];
#pragma unroll
        for (int nt = 0; nt < 4; ++nt) {
            int gate = nt * 128 + u;
            biasv[nt] = bih1[gate] + bhh1[gate];
#pragma unroll
            for (int kc = 0; kc < 4; ++kc) {
                wih[nt][kc] = load_wfrag(Wih1, gate, HDIM, kc * 32 + lg * 8, HDIM);
                whh[nt][kc] = load_wfrag(Whh1, gate, HDIM, kc * 32 + lg * 8, HDIM);
            }
        }
        __syncthreads();  // hbuf zeros visible

        const uint64_t flagu = (uint64_t)(uintptr_t)(flags + wgb * T_SEQ);
        const uint64_t xbase = (uint64_t)(uintptr_t)h1ws +
                               (uint64_t)(wgb * B_TILE + l16) * 256 + (uint64_t)lg * 16;

        // prologue: wait flag[0], flag[1]; load A(0), B(1); probe flag[2]
        unsigned pv = 0;
#pragma unroll 1
        for (int s = 0; s < 2; ++s) {
            uint64_t fa = flagu + (uint64_t)s * 4;
            do {
                asm volatile("global_load_dword %0, %1, off sc0 sc1"
                             : "=v"(pv) : "v"(fa) : "memory");
                asm volatile("s_waitcnt vmcnt(0)" ::: "memory");
            } while (pv == 0);
        }
        f16x8 xA0, xA1, xA2, xA3, xB0, xB1, xB2, xB3;
        {
            uint64_t a0 = xbase;
            asm volatile("global_load_dwordx4 %0, %1, off sc0 sc1"            : "=v"(xA0) : "v"(a0) : "memory");
            asm volatile("global_load_dwordx4 %0, %1, off offset:64 sc0 sc1"  : "=v"(xA1) : "v"(a0) : "memory");
            asm volatile("global_load_dwordx4 %0, %1, off offset:128 sc0 sc1" : "=v"(xA2) : "v"(a0) : "memory");
            asm volatile("global_load_dwordx4 %0, %1, off offset:192 sc0 sc1" : "=v"(xA3) : "v"(a0) : "memory");
            uint64_t a1 = xbase + HSTEP_BYTES;
            asm volatile("global_load_dwordx4 %0, %1, off sc0 sc1"            : "=v"(xB0) : "v"(a1) : "memory");
            asm volatile("global_load_dwordx4 %0, %1, off offset:64 sc0 sc1"  : "=v"(xB1) : "v"(a1) : "memory");
            asm volatile("global_load_dwordx4 %0, %1, off offset:128 sc0 sc1" : "=v"(xB2) : "v"(a1) : "memory");
            asm volatile("global_load_dwordx4 %0, %1, off offset:192 sc0 sc1" : "=v"(xB3) : "v"(a1) : "memory");
            uint64_t pf = flagu + 2 * 4;
            asm volatile("global_load_dword %0, %1, off sc0 sc1" : "=v"(pv) : "v"(pf) : "memory");
            vm_drain();
        }

        float hlast[4] = {0.f, 0.f, 0.f, 0.f};

        // one pipeline step: consume (c0..c3) for time t, reload same set for t+2,
        // probe flag[t+3] into pv for the NEXT step's test.
        auto cstep = [&](int t, f16x8& c0, f16x8& c1, f16x8& c2, f16x8& c3) {
            const f16* cur = hbuf[t & 1];
            f16* nxt = hbuf[(t + 1) & 1];
            f16x8 ha[4];
#pragma unroll
            for (int kc = 0; kc < 4; ++kc) {
                int chunk = kc * 4 + lg;
                ha[kc] = *(const f16x8*)(cur + l16 * HDIM + ((chunk ^ (l16 & 7)) << 3));
            }
            f32x4 acc[4];
#pragma unroll
            for (int nt = 0; nt < 4; ++nt) {
                f32x4 a = {biasv[nt], biasv[nt], biasv[nt], biasv[nt]};
                a = __builtin_amdgcn_mfma_f32_16x16x32_f16(c0, wih[nt][0], a, 0, 0, 0);
                a = __builtin_amdgcn_mfma_f32_16x16x32_f16(c1, wih[nt][1], a, 0, 0, 0);
                a = __builtin_amdgcn_mfma_f32_16x16x32_f16(c2, wih[nt][2], a, 0, 0, 0);
                a = __builtin_amdgcn_mfma_f32_16x16x32_f16(c3, wih[nt][3], a, 0, 0, 0);
                a = __builtin_amdgcn_mfma_f32_16x16x32_f16(ha[0], whh[nt][0], a, 0, 0, 0);
                a = __builtin_amdgcn_mfma_f32_16x16x32_f16(ha[1], whh[nt][1], a, 0, 0, 0);
                a = __builtin_amdgcn_mfma_f32_16x16x32_f16(ha[2], whh[nt][2], a, 0, 0, 0);
                a = __builtin_amdgcn_mfma_f32_16x16x32_f16(ha[3], whh[nt][3], a, 0, 0, 0);
                acc[nt] = a;
            }

            // drain: D(t+1) + probe(t+2) are ~1 step old -> hidden
            vm_drain();
            if (t + 2 < T_SEQ) {
                if (pv == 0) {
                    uint64_t fa = flagu + (uint64_t)(t + 2) * 4;
                    do {
                        asm volatile("global_load_dword %0, %1, off sc0 sc1"
                                     : "=v"(pv) : "v"(fa) : "memory");
                        asm volatile("s_waitcnt vmcnt(0)" ::: "memory");
                    } while (pv == 0);
                }
                uint64_t na = xbase + (uint64_t)(t + 2) * HSTEP_BYTES;
                asm volatile("global_load_dwordx4 %0, %1, off sc0 sc1"            : "=v"(c0) : "v"(na) : "memory");
                asm volatile("global_load_dwordx4 %0, %1, off offset:64 sc0 sc1"  : "=v"(c1) : "v"(na) : "memory");
                asm volatile("global_load_dwordx4 %0, %1, off offset:128 sc0 sc1" : "=v"(c2) : "v"(na) : "memory");
                asm volatile("global_load_dwordx4 %0, %1, off offset:192 sc0 sc1" : "=v"(c3) : "v"(na) : "memory");
                if (t + 3 < T_SEQ) {
                    uint64_t pf = flagu + (uint64_t)(t + 3) * 4;
                    asm volatile("global_load_dword %0, %1, off sc0 sc1"
                                 : "=v"(pv) : "v"(pf) : "memory");
                }
            }

#pragma unroll
            for (int r = 0; r < 4; ++r) {
                float iv = sigm(acc[0][r]);
                float fv = sigm(acc[1][r]);
                float gv = tanh_fast(acc[2][r]);
                float ov = sigm(acc[3][r]);
                float cn = fv * cst[r] + iv * gv;
                cst[r] = cn;
                float hv = ov * tanh_fast(cn);
                hlast[r] = hv;
                int br = lg * 4 + r;
                nxt[br * HDIM + ((((unsigned)u >> 3) ^ (br & 7)) << 3) + (u & 7)] = (f16)hv;
            }
            wg_barrier_lds();
        };

        for (int t = 0; t < T_SEQ; t += 2) {
            cstep(t,     xA0, xA1, xA2, xA3);
            cstep(t + 1, xB0, xB1, xB2, xB3);
        }

        // ================= FC head on h2[:, T-1, :] =================
#pragma unroll
        for (int r = 0; r < 4; ++r) h2buf[lg * 4 + r][u] = hlast[r];
        __syncthreads();

        for (int i = tid; i < 16 * 64; i += 512) {
            int b = i >> 6, o = i & 63;
            float s = fc1b[o];
            for (int k = 0; k < HDIM; ++k) s += h2buf[b][k] * fc1w[o * HDIM + k];
            a1buf[b][o] = fmaxf(s, 0.f);
        }
        __syncthreads();
        if (tid < 16 * 32) {
            int b = tid >> 5, o = tid & 31;
            float s = fc2b[o];
            for (int k = 0; k < 64; ++k) s += a1buf[b][k] * fc2w[o * 64 + k];
            a2buf[b][o] = fmaxf(s, 0.f);
        }
        __syncthreads();
        if (tid < 32) {
            int b = tid >> 1, o = tid & 1;
            float s = fc3b[o];
            for (int k = 0; k < 32; ++k) s += a2buf[b][k] * fc3w[o * 32 + k];
            out[(wgb * B_TILE + b) * 2 + o] = s;
        }
    }
}

extern "C" void kernel_launch(void* const* d_in, const int* in_sizes, int n_in,
                              void* d_out, int out_size, void* d_ws, size_t ws_size,
                              hipStream_t stream)
{
    const float* x    = (const float*)d_in[0];
    const float* Wih0 = (const float*)d_in[1];
    const float* Whh0 = (const float*)d_in[2];
    const float* bih0 = (const float*)d_in[3];
    const float* bhh0 = (const float*)d_in[4];
    const float* Wih1 = (const float*)d_in[5];
    const float* Whh1 = (const float*)d_in[6];
    const float* bih1 = (const float*)d_in[7];
    const float* bhh1 = (const float*)d_in[8];
    const float* fc1w = (const float*)d_in[9];
    const float* fc1b = (const float*)d_in[10];
    const float* fc2w = (const float*)d_in[11];
    const float* fc2b = (const float*)d_in[12];
    const float* fc3w = (const float*)d_in[13];
    const float* fc3b = (const float*)d_in[14];

    f16* xT    = (f16*)d_ws;
    f16* h1    = (f16*)((char*)d_ws + XT_BYTES);
    int* flags = (int*)((char*)d_ws + FLAGS_OFF);

    // flags must be zero at the start of every launch (replays included)
    hipMemsetAsync(flags, 0, FLAGS_BYTES, stream);
    k_prep<<<B_ALL, 256, 0, stream>>>(x, xT);
    k_lstm<<<N_WG_TOT, 512, 0, stream>>>(xT, h1, flags, Wih0, Whh0, bih0, bhh0,
                                         Wih1, Whh1, bih1, bhh1,
                                         fc1w, fc1b, fc2w, fc2b, fc3w, fc3b,
                                         (float*)d_out);
}